// Round 3
// baseline (188.856 us; speedup 1.0000x reference)
//
#include <hip/hip_runtime.h>

#define NN 2048
#define HALF 1024
#define CC 128
#define EE 65536
#define CAP 128

typedef unsigned short u16;

__device__ __forceinline__ float sigm(float v){ return 1.0f/(1.0f + __expf(-v)); }

// ---------------- K1: colsum of sigmoid(my[:1024,:1024]) over rows (blocks 0..63) | edge bucketing (64..319)
__global__ __launch_bounds__(256) void k_prep(
    const float* __restrict__ my, const int* __restrict__ ei,
    float* __restrict__ colsum, int* __restrict__ cnt, u16* __restrict__ bucket)
{
  int b = blockIdx.x, t = threadIdx.x;
  if (b < 64) {
    int cb = b & 3, rb = b >> 2;
    int c = cb*256 + t;
    const float* p = my + (size_t)(rb*64)*NN + c;
    float s = 0.f;
    #pragma unroll 4
    for (int r=0;r<64;r++) s += sigm(p[(size_t)r*NN]);
    atomicAdd(&colsum[c], s);
  } else {
    int e = (b-64)*256 + t;
    int s = ei[e], d = ei[EE + e];
    int slot = atomicAdd(&cnt[d], 1);
    if (slot < CAP) bucket[d*CAP + slot] = (u16)s;
  }
}

// ---------------- K2: dinv = rsqrt(1 + cnt + colsum)
__global__ __launch_bounds__(256) void k_dinv(const float* __restrict__ colsum,
                                              const int* __restrict__ cnt,
                                              float* __restrict__ dinv){
  int i = blockIdx.x*256 + threadIdx.x;
  float s = 1.0f + (float)cnt[i] + (i < HALF ? colsum[i] : 0.0f);
  dinv[i] = rsqrtf(s);
}

// self + sparse-neighbor aggregation for one (row d, feature f)
__device__ __forceinline__ void agg_row(
  const float* __restrict__ feat, const float* __restrict__ dinv,
  const int* __restrict__ cnt, const u16* __restrict__ bucket,
  float* __restrict__ AGG, int d, int f)
{
  float dd = dinv[d];
  float acc = dd * feat[(size_t)d*CC + f];
  int m = cnt[d]; m = m > CAP ? CAP : m;
  const u16* bk = bucket + d*CAP;
  for (int j=0;j<m;j++){
    int s = bk[j];
    acc += dinv[s] * feat[(size_t)s*CC + f];
  }
  AGG[(size_t)d*CC + f] = dd * acc;
}

// ---------------- K3: Sp[r][c] = sigm(my[r][c])*dinv[r]*dinv[c] (blocks 0..4095) | agg of x (4096..5119)
__global__ __launch_bounds__(256) void k_spagg(
  const float* __restrict__ my, const float* __restrict__ x, const float* __restrict__ dinv,
  const int* __restrict__ cnt, const u16* __restrict__ bucket,
  float* __restrict__ Sp, float* __restrict__ AGG)
{
  int b = blockIdx.x, t = threadIdx.x;
  if (b < 4096) {
    int idx = b*256 + t;
    int r = idx >> 10, c = idx & 1023;
    Sp[idx] = sigm(my[(size_t)r*NN + c]) * dinv[r] * dinv[c];
  } else {
    int d = (b-4096)*2 + (t>>7);
    agg_row(x, dinv, cnt, bucket, AGG, d, t & 127);
  }
}

// ---------------- K6: agg of hidden (1024 blocks x 2 rows)
__global__ __launch_bounds__(256) void k_agg(
  const float* __restrict__ feat, const float* __restrict__ dinv,
  const int* __restrict__ cnt, const u16* __restrict__ bucket,
  float* __restrict__ AGG)
{
  int d = blockIdx.x*2 + (threadIdx.x>>7);
  agg_row(feat, dinv, cnt, bucket, AGG, d, threadIdx.x & 127);
}

// ---------------- dense part: AGG[d][f] += sum_r Sp[r][d] * F[r][f]   (vector f32, r-split 4)
__global__ __launch_bounds__(256) void k_gemm(
  const float* __restrict__ Sp, const float* __restrict__ F, float* __restrict__ AGG)
{
  int t = threadIdx.x;
  int f = t & 127, half = t >> 7;
  int dbase = blockIdx.x*16 + half*8;
  int r0 = blockIdx.y*256;
  float acc[8];
  #pragma unroll
  for (int j=0;j<8;j++) acc[j] = 0.f;
  #pragma unroll 4
  for (int r=r0; r<r0+256; ++r){
    float fv = F[(size_t)r*CC + f];
    const float4* sp4 = (const float4*)(Sp + (size_t)r*HALF + dbase);
    float4 s0 = sp4[0], s1 = sp4[1];
    acc[0] = fmaf(s0.x, fv, acc[0]);
    acc[1] = fmaf(s0.y, fv, acc[1]);
    acc[2] = fmaf(s0.z, fv, acc[2]);
    acc[3] = fmaf(s0.w, fv, acc[3]);
    acc[4] = fmaf(s1.x, fv, acc[4]);
    acc[5] = fmaf(s1.y, fv, acc[5]);
    acc[6] = fmaf(s1.z, fv, acc[6]);
    acc[7] = fmaf(s1.w, fv, acc[7]);
  }
  #pragma unroll
  for (int j=0;j<8;j++)
    atomicAdd(&AGG[(size_t)(dbase+j)*CC + f], acc[j]);
}

// ---------------- hidden = relu(AGG @ W1 + b1)
__global__ __launch_bounds__(256) void k_hidden(
  const float* __restrict__ AGG, const float* __restrict__ W1, const float* __restrict__ b1,
  float* __restrict__ hid)
{
  __shared__ float la[2][CC];
  int t = threadIdx.x;
  int rloc = t >> 7, k = t & 127;
  int row = blockIdx.x*2 + rloc;
  la[rloc][k] = AGG[(size_t)row*CC + k];
  __syncthreads();
  int f = k;
  float acc = b1[f];
  const float* ar = la[rloc];
  #pragma unroll 8
  for (int kk=0;kk<CC;kk++) acc = fmaf(ar[kk], W1[kk*CC + f], acc);
  hid[(size_t)row*CC + f] = acc > 0.f ? acc : 0.f;
}

// ---------------- z = AGG @ [Wmu|Wls] + [bmu|bls] -> out (f32, concatenated)
__global__ __launch_bounds__(256) void k_z(
  const float* __restrict__ AGG, const float* __restrict__ Wmu, const float* __restrict__ bmu,
  const float* __restrict__ Wls, const float* __restrict__ bls,
  float* __restrict__ out)
{
  __shared__ float la[2][CC];
  int t = threadIdx.x;
  int rloc = t >> 7, k = t & 127;
  int row = blockIdx.x*2 + rloc;
  la[rloc][k] = AGG[(size_t)row*CC + k];
  __syncthreads();
  int f = k;
  const float* ar = la[rloc];
  if (f < 64) {
    float acc = bmu[f];
    #pragma unroll 8
    for (int kk=0;kk<CC;kk++) acc = fmaf(ar[kk], Wmu[kk*64 + f], acc);
    out[(size_t)row*64 + f] = acc;
  } else {
    int g = f - 64;
    float acc = bls[g];
    #pragma unroll 8
    for (int kk=0;kk<CC;kk++) acc = fmaf(ar[kk], Wls[kk*64 + g], acc);
    out[(size_t)NN*64 + (size_t)row*64 + g] = acc;
  }
}

extern "C" void kernel_launch(void* const* d_in, const int* in_sizes, int n_in,
                              void* d_out, int out_size, void* d_ws, size_t ws_size,
                              hipStream_t stream)
{
  (void)in_sizes; (void)n_in; (void)out_size; (void)ws_size;
  const float* x   = (const float*)d_in[0];
  const float* my  = (const float*)d_in[1];
  const float* W1  = (const float*)d_in[2];
  const float* b1  = (const float*)d_in[3];
  const float* Wmu = (const float*)d_in[4];
  const float* bmu = (const float*)d_in[5];
  const float* Wls = (const float*)d_in[6];
  const float* bls = (const float*)d_in[7];
  const int*   ei  = (const int*)d_in[8];
  float* out = (float*)d_out;
  char* ws = (char*)d_ws;

  // ws layout (total 6,836,224 B = 6.5 MB)
  float* colsum = (float*)(ws + 0);        //    4096 B (memset 0)
  int*   cnt    = (int*)  (ws + 4096);     //    8192 B (memset 0)
  float* dinv   = (float*)(ws + 12288);    //    8192 B
  u16*   bucket = (u16*)  (ws + 20480);    //  524288 B
  float* Sp     = (float*)(ws + 544768);   // 4194304 B
  float* AGG    = (float*)(ws + 4739072);  // 1048576 B
  float* hid    = (float*)(ws + 5787648);  // 1048576 B

  hipMemsetAsync(ws, 0, 12288, stream);
  k_prep<<<320, 256, 0, stream>>>(my, ei, colsum, cnt, bucket);
  k_dinv<<<8, 256, 0, stream>>>(colsum, cnt, dinv);
  k_spagg<<<5120, 256, 0, stream>>>(my, x, dinv, cnt, bucket, Sp, AGG);
  k_gemm<<<dim3(64, 4), 256, 0, stream>>>(Sp, x, AGG);
  k_hidden<<<1024, 256, 0, stream>>>(AGG, W1, b1, hid);
  k_agg<<<1024, 256, 0, stream>>>(hid, dinv, cnt, bucket, AGG);
  k_gemm<<<dim3(64, 4), 256, 0, stream>>>(Sp, hid, AGG);
  k_z<<<1024, 256, 0, stream>>>(AGG, Wmu, bmu, Wls, bls, out);
}